// Round 3
// baseline (230.707 us; speedup 1.0000x reference)
//
#include <hip/hip_runtime.h>

#define LYS 12
#define LXS 120   // 10*LYS; strides ≡ 0 mod 4 words -> aligned ds_read_b128 line reads

// ---- 27 weight taps as individually-named float4 SSA values (NO array: R1/R2
// showed the compiler demotes a w[27] array to scratch -> latency-bound loop,
// VGPR=84 < the 108 needed for residency). ----
#define REPEAT27(M) M(0) M(1) M(2) M(3) M(4) M(5) M(6) M(7) M(8) M(9) M(10) \
    M(11) M(12) M(13) M(14) M(15) M(16) M(17) M(18) M(19) M(20) M(21) M(22) \
    M(23) M(24) M(25) M(26)

#define LOADW(T) float4 w##T = *(const float4*)(W + ((size_t)(T) << 18) + ofs);
#define ACCW(T)  sw0 += w##T.x; sw1 += w##T.y; sw2 += w##T.z; sw3 += w##T.w;
#define PINW(T)  asm("" : "+v"(w##T.x), "+v"(w##T.y), "+v"(w##T.z), "+v"(w##T.w));

// one (dx,dy) line: 6-float z-window, 16B-aligned (lz=4h), 12 FMAs, 3 taps
#define LINE(dx, dy, WA, WB, WC) {                                          \
    const float* p = &blk[(lx + (dx)) * LXS + (ly + (dy)) * LYS + 4 * h];   \
    const float4 va = *(const float4*)p;                                    \
    const float2 vb = *(const float2*)(p + 4);                              \
    d0 += va.x * WA.x; d1 += va.y * WA.y; d2 += va.z * WA.z; d3 += va.w * WA.w; \
    d0 += va.y * WB.x; d1 += va.z * WB.y; d2 += va.w * WB.z; d3 += vb.x * WB.w; \
    d0 += va.z * WC.x; d1 += va.w * WC.y; d2 += vb.x * WC.z; d3 += vb.y * WC.w; }

__global__ __launch_bounds__(128, 3)
void gridnet_kernel(const float* __restrict__ W,
                    const float* __restrict__ Bias,
                    const float* __restrict__ Rs,
                    const float* __restrict__ X,
                    float* __restrict__ Y,
                    int n_batch)
{
    __shared__ __align__(16) float blk[10 * LXS];
    __shared__ float4 red4[2];
    __shared__ float2 red2[2];

    const int tid  = threadIdx.x;
    const int h    = tid & 1;            // z-half: outputs z = 4h..4h+3
    const int ly   = (tid >> 1) & 7;
    const int lx   = tid >> 4;
    const int wave = tid >> 6;
    const int lane = tid & 63;

    const int bid   = blockIdx.x;
    const int r     = bid / n_batch;     // spatial block 0..511
    const int batch = bid - r * n_batch; // batch-fast: 16 weight-sharers adjacent
    const int gm0 = (r >> 6) << 3;
    const int gn0 = ((r >> 3) & 7) << 3;
    const int gk0 = (r & 7) << 3;

    const float* xb = X + ((size_t)batch << 18);

    // ---- stage 10x10x10 raw block (zero halo) into LDS; total sums on the fly ----
    float s_all = 0.f, q_all = 0.f;
    for (int i = tid; i < 1000; i += 128) {
        int ix = i / 100;
        int rem = i - ix * 100;
        int iy = rem / 10;
        int iz = rem - iy * 10;
        int m = gm0 + ix - 1, n = gn0 + iy - 1, k = gk0 + iz - 1;
        float v = 0.f;
        if ((unsigned)m < 64u && (unsigned)n < 64u && (unsigned)k < 64u)
            v = xb[(m << 12) + (n << 6) + k];
        blk[ix * LXS + iy * LYS + iz] = v;
        s_all += v;
        q_all += v * v;
    }

    // ---- per-thread params: 27 taps x 4 z, register-resident for all 8 iters ----
    const int gm = gm0 + lx, gn = gn0 + ly, gk = gk0 + 4 * h;
    const size_t ofs = ((size_t)gm << 12) + (gn << 6) + gk;

    REPEAT27(LOADW)
    float sw0 = 0.f, sw1 = 0.f, sw2 = 0.f, sw3 = 0.f;
    REPEAT27(ACCW)
    float4 b4 = *(const float4*)(Bias + ofs);
    float4 r4 = *(const float4*)(Rs + ofs);
    REPEAT27(PINW)
    asm("" : "+v"(b4.x), "+v"(b4.y), "+v"(b4.z), "+v"(b4.w));
    asm("" : "+v"(r4.x), "+v"(r4.y), "+v"(r4.z), "+v"(r4.w));
    asm("" : "+v"(sw0), "+v"(sw1), "+v"(sw2), "+v"(sw3));

    __syncthreads();

    const int ip = (lx + 1) * LXS + (ly + 1) * LYS + (4 * h + 1);
    float c0 = blk[ip], c1 = blk[ip + 1], c2 = blk[ip + 2], c3 = blk[ip + 3];

    // ---- one-time reduction: total + interior sums -> frozen halo sums ----
    float a0 = s_all, a1 = q_all;
    float a2 = c0 + c1 + c2 + c3;
    float a3 = c0 * c0 + c1 * c1 + c2 * c2 + c3 * c3;
    #pragma unroll
    for (int off = 32; off; off >>= 1) {
        a0 += __shfl_xor(a0, off);
        a1 += __shfl_xor(a1, off);
        a2 += __shfl_xor(a2, off);
        a3 += __shfl_xor(a3, off);
    }
    if (lane == 0) red4[wave] = make_float4(a0, a1, a2, a3);
    __syncthreads();
    float4 t0 = red4[0], t1 = red4[1];
    const float halo_s = (t0.x + t1.x) - (t0.z + t1.z);
    const float halo_q = (t0.y + t1.y) - (t0.w + t1.w);
    float Si = t0.z + t1.z;
    float Qi = t0.w + t1.w;

    const float inv_n = 1.0f / 1000.0f;

    #pragma unroll 1
    for (int it = 0; it < 8; ++it) {
        float mean = (halo_s + Si) * inv_n;
        float e2   = (halo_q + Qi) * inv_n;
        float istd = rsqrtf(e2 - mean * mean + 1e-5f);

        // 27-tap dot on RAW values; norm folded: sum w*(v-mean)*istd = istd*(dot - mean*sumw)
        float d0 = 0.f, d1 = 0.f, d2 = 0.f, d3 = 0.f;
        LINE(0, 0, w0,  w1,  w2)
        LINE(0, 1, w3,  w4,  w5)
        LINE(0, 2, w6,  w7,  w8)
        LINE(1, 0, w9,  w10, w11)
        LINE(1, 1, w12, w13, w14)
        LINE(1, 2, w15, w16, w17)
        LINE(2, 0, w18, w19, w20)
        LINE(2, 1, w21, w22, w23)
        LINE(2, 2, w24, w25, w26)

        float u0 = (d0 - mean * sw0) * istd + b4.x;
        float u1 = (d1 - mean * sw1) * istd + b4.y;
        float u2 = (d2 - mean * sw2) * istd + b4.z;
        float u3 = (d3 - mean * sw3) * istd + b4.w;
        c0 += r4.x * (u0 / (1.f + __expf(-u0)));
        c1 += r4.y * (u1 / (1.f + __expf(-u1)));
        c2 += r4.z * (u2 / (1.f + __expf(-u2)));
        c3 += r4.w * (u3 / (1.f + __expf(-u3)));

        __syncthreads();                  // all reads of old block done
        blk[ip]     = c0;
        blk[ip + 1] = c1;
        blk[ip + 2] = c2;
        blk[ip + 3] = c3;

        float b0 = c0 + c1 + c2 + c3;
        float b1 = c0 * c0 + c1 * c1 + c2 * c2 + c3 * c3;
        #pragma unroll
        for (int off = 32; off; off >>= 1) {
            b0 += __shfl_xor(b0, off);
            b1 += __shfl_xor(b1, off);
        }
        if (lane == 0) red2[wave] = make_float2(b0, b1);
        __syncthreads();                  // writes + partial sums visible
        Si = red2[0].x + red2[1].x;
        Qi = red2[0].y + red2[1].y;
    }

    *(float4*)(Y + ((size_t)batch << 18) + ofs) = make_float4(c0, c1, c2, c3);
}

extern "C" void kernel_launch(void* const* d_in, const int* in_sizes, int n_in,
                              void* d_out, int out_size, void* d_ws, size_t ws_size,
                              hipStream_t stream) {
    const float* W = (const float*)d_in[0];   // (27,64,64,64)
    const float* B = (const float*)d_in[1];   // (64,64,64)
    const float* R = (const float*)d_in[2];   // (64,64,64)
    const float* X = (const float*)d_in[3];   // (16,64,64,64)
    float* Y = (float*)d_out;

    int n_batch = in_sizes[3] >> 18;          // 64^3 per sample
    dim3 grid(512 * n_batch), block(128);
    hipLaunchKernelGGL(gridnet_kernel, grid, block, 0, stream, W, B, R, X, Y, n_batch);
}

// Round 4
// 187.675 us; speedup vs baseline: 1.2293x; 1.2293x over previous
//
#include <hip/hip_runtime.h>

#define LYS 12
#define LXS 120   // 10*LYS; strides ≡ 0 mod 4 words -> aligned ds_read_b128 line reads

// ---- 27 weight taps as individually-named float4 SSA values (no array:
// arrays get demoted to scratch). Register residency across the 8-iter loop
// is enforced by amdgpu_waves_per_eu(3,3): the allocator's default target is
// 6 waves/EU = 84 VGPRs (measured R2/R3), met by remat (R2: 3.5GB L2 weight
// re-reads, L2-BW-bound) or spill (R3: WRITE_SIZE 58MB). (3,3) -> 168-reg
// budget > ~155 live -> loads stay hoisted. ----
#define REPEAT27(M) M(0) M(1) M(2) M(3) M(4) M(5) M(6) M(7) M(8) M(9) M(10) \
    M(11) M(12) M(13) M(14) M(15) M(16) M(17) M(18) M(19) M(20) M(21) M(22) \
    M(23) M(24) M(25) M(26)

#define LOADW(T) float4 w##T = *(const float4*)(W + ((size_t)(T) << 18) + ofs);
#define ACCW(T)  sw0 += w##T.x; sw1 += w##T.y; sw2 += w##T.z; sw3 += w##T.w;

// one (dx,dy) line: 6-float z-window, 16B-aligned (lz=4h), 12 FMAs, 3 taps
#define LINE(dx, dy, WA, WB, WC) {                                          \
    const float* p = &blk[(lx + (dx)) * LXS + (ly + (dy)) * LYS + 4 * h];   \
    const float4 va = *(const float4*)p;                                    \
    const float2 vb = *(const float2*)(p + 4);                              \
    d0 += va.x * WA.x; d1 += va.y * WA.y; d2 += va.z * WA.z; d3 += va.w * WA.w; \
    d0 += va.y * WB.x; d1 += va.z * WB.y; d2 += va.w * WB.z; d3 += vb.x * WB.w; \
    d0 += va.z * WC.x; d1 += va.w * WC.y; d2 += vb.x * WC.z; d3 += vb.y * WC.w; }

__global__ __launch_bounds__(128)
__attribute__((amdgpu_waves_per_eu(3, 3)))
void gridnet_kernel(const float* __restrict__ W,
                    const float* __restrict__ Bias,
                    const float* __restrict__ Rs,
                    const float* __restrict__ X,
                    float* __restrict__ Y,
                    int n_batch)
{
    __shared__ __align__(16) float blk[10 * LXS];
    __shared__ float4 red4[2];
    __shared__ float2 red2[2];

    const int tid  = threadIdx.x;
    const int h    = tid & 1;            // z-half: outputs z = 4h..4h+3
    const int ly   = (tid >> 1) & 7;
    const int lx   = tid >> 4;
    const int wave = tid >> 6;
    const int lane = tid & 63;

    const int bid   = blockIdx.x;
    const int r     = bid / n_batch;     // spatial block 0..511
    const int batch = bid - r * n_batch; // batch-fast: 16 weight-sharers adjacent
    const int gm0 = (r >> 6) << 3;
    const int gn0 = ((r >> 3) & 7) << 3;
    const int gk0 = (r & 7) << 3;

    const float* xb = X + ((size_t)batch << 18);

    // ---- stage 10x10x10 raw block (zero halo) into LDS; total sums on the fly ----
    float s_all = 0.f, q_all = 0.f;
    for (int i = tid; i < 1000; i += 128) {
        int ix = i / 100;
        int rem = i - ix * 100;
        int iy = rem / 10;
        int iz = rem - iy * 10;
        int m = gm0 + ix - 1, n = gn0 + iy - 1, k = gk0 + iz - 1;
        float v = 0.f;
        if ((unsigned)m < 64u && (unsigned)n < 64u && (unsigned)k < 64u)
            v = xb[(m << 12) + (n << 6) + k];
        blk[ix * LXS + iy * LYS + iz] = v;
        s_all += v;
        q_all += v * v;
    }

    // ---- per-thread params: 27 taps x 4 z, register-resident for all 8 iters ----
    const int gm = gm0 + lx, gn = gn0 + ly, gk = gk0 + 4 * h;
    const size_t ofs = ((size_t)gm << 12) + (gn << 6) + gk;

    REPEAT27(LOADW)
    float sw0 = 0.f, sw1 = 0.f, sw2 = 0.f, sw3 = 0.f;
    REPEAT27(ACCW)
    float4 b4 = *(const float4*)(Bias + ofs);
    float4 r4 = *(const float4*)(Rs + ofs);

    __syncthreads();

    const int ip = (lx + 1) * LXS + (ly + 1) * LYS + (4 * h + 1);
    float c0 = blk[ip], c1 = blk[ip + 1], c2 = blk[ip + 2], c3 = blk[ip + 3];

    // ---- one-time reduction: total + interior sums -> frozen halo sums ----
    float a0 = s_all, a1 = q_all;
    float a2 = c0 + c1 + c2 + c3;
    float a3 = c0 * c0 + c1 * c1 + c2 * c2 + c3 * c3;
    #pragma unroll
    for (int off = 32; off; off >>= 1) {
        a0 += __shfl_xor(a0, off);
        a1 += __shfl_xor(a1, off);
        a2 += __shfl_xor(a2, off);
        a3 += __shfl_xor(a3, off);
    }
    if (lane == 0) red4[wave] = make_float4(a0, a1, a2, a3);
    __syncthreads();
    float4 t0 = red4[0], t1 = red4[1];
    const float halo_s = (t0.x + t1.x) - (t0.z + t1.z);
    const float halo_q = (t0.y + t1.y) - (t0.w + t1.w);
    float Si = t0.z + t1.z;
    float Qi = t0.w + t1.w;

    const float inv_n = 1.0f / 1000.0f;

    #pragma unroll 1
    for (int it = 0; it < 8; ++it) {
        float mean = (halo_s + Si) * inv_n;
        float e2   = (halo_q + Qi) * inv_n;
        float istd = rsqrtf(e2 - mean * mean + 1e-5f);

        // 27-tap dot on RAW values; norm folded: sum w*(v-mean)*istd = istd*(dot - mean*sumw)
        float d0 = 0.f, d1 = 0.f, d2 = 0.f, d3 = 0.f;
        LINE(0, 0, w0,  w1,  w2)
        LINE(0, 1, w3,  w4,  w5)
        LINE(0, 2, w6,  w7,  w8)
        LINE(1, 0, w9,  w10, w11)
        LINE(1, 1, w12, w13, w14)
        LINE(1, 2, w15, w16, w17)
        LINE(2, 0, w18, w19, w20)
        LINE(2, 1, w21, w22, w23)
        LINE(2, 2, w24, w25, w26)

        float u0 = (d0 - mean * sw0) * istd + b4.x;
        float u1 = (d1 - mean * sw1) * istd + b4.y;
        float u2 = (d2 - mean * sw2) * istd + b4.z;
        float u3 = (d3 - mean * sw3) * istd + b4.w;
        c0 += r4.x * (u0 / (1.f + __expf(-u0)));
        c1 += r4.y * (u1 / (1.f + __expf(-u1)));
        c2 += r4.z * (u2 / (1.f + __expf(-u2)));
        c3 += r4.w * (u3 / (1.f + __expf(-u3)));

        __syncthreads();                  // all reads of old block done
        blk[ip]     = c0;
        blk[ip + 1] = c1;
        blk[ip + 2] = c2;
        blk[ip + 3] = c3;

        float b0 = c0 + c1 + c2 + c3;
        float b1 = c0 * c0 + c1 * c1 + c2 * c2 + c3 * c3;
        #pragma unroll
        for (int off = 32; off; off >>= 1) {
            b0 += __shfl_xor(b0, off);
            b1 += __shfl_xor(b1, off);
        }
        if (lane == 0) red2[wave] = make_float2(b0, b1);
        __syncthreads();                  // writes + partial sums visible
        Si = red2[0].x + red2[1].x;
        Qi = red2[0].y + red2[1].y;
    }

    *(float4*)(Y + ((size_t)batch << 18) + ofs) = make_float4(c0, c1, c2, c3);
}

extern "C" void kernel_launch(void* const* d_in, const int* in_sizes, int n_in,
                              void* d_out, int out_size, void* d_ws, size_t ws_size,
                              hipStream_t stream) {
    const float* W = (const float*)d_in[0];   // (27,64,64,64)
    const float* B = (const float*)d_in[1];   // (64,64,64)
    const float* R = (const float*)d_in[2];   // (64,64,64)
    const float* X = (const float*)d_in[3];   // (16,64,64,64)
    float* Y = (float*)d_out;

    int n_batch = in_sizes[3] >> 18;          // 64^3 per sample
    dim3 grid(512 * n_batch), block(128);
    hipLaunchKernelGGL(gridnet_kernel, grid, block, 0, stream, W, B, R, X, Y, n_batch);
}